// Round 4
// baseline (2507.442 us; speedup 1.0000x reference)
//
#include <hip/hip_runtime.h>
#include <hip/hip_bf16.h>
#include <math.h>

using bf16 = __hip_bfloat16;
typedef __bf16 bf16x8 __attribute__((ext_vector_type(8)));
typedef float f32x4 __attribute__((ext_vector_type(4)));

static constexpr int TOK = 16 * 56 * 56;   // 50176 tokens
static constexpr int CDIM = 384;
static constexpr float SCALE = 0.17677669529663687f; // 32^-0.5

// ---------------- dtype detector: flag=1 if inputs are bf16, 0 if fp32 ----------------
__global__ void k_detect(const unsigned short* __restrict__ w, int* __restrict__ flag) {
    int l = threadIdx.x;   // 64 threads
    int cnt = 0;
    for (int i = l; i < 4096; i += 64) {
        int e = (w[i] >> 7) & 0xFF;          // bf16 exponent field
        if (e >= 0xC0) cnt++;                // |v| >= 2^65: impossible for real weights
    }
#pragma unroll
    for (int off = 32; off; off >>= 1) cnt += __shfl_xor(cnt, off, 64);
    if (l == 0) *flag = (cnt > 16) ? 0 : 1;
}

__device__ __forceinline__ float ldany(const void* p, size_t i, int isbf) {
    return isbf ? __bfloat162float(((const bf16*)p)[i]) : ((const float*)p)[i];
}

// ---------------- convert raw input (element offset eoff) -> fp32 ----------------
__global__ void k_cvt(const void* __restrict__ x, float* __restrict__ o, int n,
                      const int* __restrict__ flag) {
    int isbf = *flag;
    int i = blockIdx.x * blockDim.x + threadIdx.x;
    int stride = gridDim.x * blockDim.x;
    for (; i < n; i += stride) o[i] = ldany(x, i, isbf);
}

// ---------------- weight transpose raw [K,N] (+eoff) -> bf16 [N,K] ----------------
__global__ void k_transpose(const void* __restrict__ in, bf16* __restrict__ out,
                            int K, int N, size_t eoff, const int* __restrict__ flag) {
    int isbf = *flag;
    int idx = blockIdx.x * 256 + threadIdx.x;
    if (idx >= K * N) return;
    int k = idx / N, n = idx - k * N;
    out[(size_t)n * K + k] = __float2bfloat16(ldany(in, eoff + idx, isbf));
}

// ---------------- LayerNorm (+ optional roll + window partition) ----------------
__global__ __launch_bounds__(256) void k_ln(const float* __restrict__ xres,
                                            const float* __restrict__ g,
                                            const float* __restrict__ bta,
                                            bf16* __restrict__ out,
                                            int shift, int windowed) {
    int wave = threadIdx.x >> 6, l = threadIdx.x & 63;
    int t = blockIdx.x * 4 + wave;
    int src;
    if (windowed) {
        int wi = t / 49, n = t - wi * 49;
        int b_ = wi >> 6, w64 = wi & 63;
        int wy = w64 >> 3, wx = w64 & 7;
        int pin = n / 7, qin = n - pin * 7;
        int hs = wy * 7 + pin + shift; if (hs >= 56) hs -= 56;
        int ws2 = wx * 7 + qin + shift; if (ws2 >= 56) ws2 -= 56;
        src = b_ * 3136 + hs * 56 + ws2;
    } else {
        src = t;
    }
    const float* xr = xres + (size_t)src * CDIM;
    float v[6];
    float s = 0.f;
#pragma unroll
    for (int j = 0; j < 6; j++) { v[j] = xr[j * 64 + l]; s += v[j]; }
#pragma unroll
    for (int off = 32; off; off >>= 1) s += __shfl_xor(s, off, 64);
    float mean = s * (1.f / 384.f);
    float sq = 0.f;
#pragma unroll
    for (int j = 0; j < 6; j++) { float d = v[j] - mean; sq += d * d; }
#pragma unroll
    for (int off = 32; off; off >>= 1) sq += __shfl_xor(sq, off, 64);
    float rstd = rsqrtf(sq * (1.f / 384.f) + 1e-5f);
    bf16* op = out + (size_t)t * CDIM;
#pragma unroll
    for (int j = 0; j < 6; j++) {
        int c = j * 64 + l;
        float val = (v[j] - mean) * rstd * g[c] + bta[c];
        op[c] = __float2bfloat16(val);
    }
}

// ---------------- MFMA GEMM: A[M,K] bf16 x Bt[N,K] bf16 -> epilogue ----------------
#define GM_QKV    0
#define GM_PROJ   1
#define GM_FC1    2
#define GM_FC2    3
#define GM_FC2OUT 4

__global__ __launch_bounds__(256) void k_gemm(
    const bf16* __restrict__ A, const bf16* __restrict__ Bt,
    const float* __restrict__ bias, int K, int Nout,
    bf16* __restrict__ obf, float* __restrict__ xres, void* __restrict__ ofinal,
    int mode, int shift, int m_base, const int* __restrict__ flag) {
    __shared__ __align__(16) bf16 As[128 * 32];
    __shared__ __align__(16) bf16 Bs[128 * 32];
    int tid = threadIdx.x;
    int w = tid >> 6, l = tid & 63;
    int m0 = blockIdx.x * 128, n0 = blockIdx.y * 128;
    int wm = (w >> 1) * 64, wn = (w & 1) * 64;
    int isbf = *flag;

    f32x4 acc[4][4];
#pragma unroll
    for (int i = 0; i < 4; i++)
#pragma unroll
        for (int j = 0; j < 4; j++) acc[i][j] = f32x4{0.f, 0.f, 0.f, 0.f};

    int s0 = tid, s1 = tid + 256;
    int ar0 = s0 >> 2, ac0 = (s0 & 3) * 8;
    int ar1 = s1 >> 2, ac1 = (s1 & 3) * 8;
    const bf16* Ap0 = A + (size_t)(m0 + ar0) * K + ac0;
    const bf16* Ap1 = A + (size_t)(m0 + ar1) * K + ac1;
    const bf16* Bp0 = Bt + (size_t)(n0 + ar0) * K + ac0;
    const bf16* Bp1 = Bt + (size_t)(n0 + ar1) * K + ac1;

    int q = l >> 4, r = l & 15;

    for (int kt = 0; kt < K; kt += 32) {
        bf16x8 va0 = *(const bf16x8*)(Ap0 + kt);
        bf16x8 va1 = *(const bf16x8*)(Ap1 + kt);
        bf16x8 vb0 = *(const bf16x8*)(Bp0 + kt);
        bf16x8 vb1 = *(const bf16x8*)(Bp1 + kt);
        __syncthreads();
        *(bf16x8*)&As[ar0 * 32 + ac0] = va0;
        *(bf16x8*)&As[ar1 * 32 + ac1] = va1;
        *(bf16x8*)&Bs[ar0 * 32 + ac0] = vb0;
        *(bf16x8*)&Bs[ar1 * 32 + ac1] = vb1;
        __syncthreads();
        bf16x8 af[4], bfr[4];
#pragma unroll
        for (int mi = 0; mi < 4; mi++)
            af[mi] = *(const bf16x8*)&As[(wm + mi * 16 + r) * 32 + q * 8];
#pragma unroll
        for (int ni = 0; ni < 4; ni++)
            bfr[ni] = *(const bf16x8*)&Bs[(wn + ni * 16 + r) * 32 + q * 8];
#pragma unroll
        for (int mi = 0; mi < 4; mi++)
#pragma unroll
            for (int ni = 0; ni < 4; ni++)
                acc[mi][ni] = __builtin_amdgcn_mfma_f32_16x16x32_bf16(
                    af[mi], bfr[ni], acc[mi][ni], 0, 0, 0);
    }

    // epilogue: C/D layout col = lane&15, row = (lane>>4)*4 + reg
#pragma unroll
    for (int mi = 0; mi < 4; mi++) {
#pragma unroll
        for (int ni = 0; ni < 4; ni++) {
#pragma unroll
            for (int rr = 0; rr < 4; rr++) {
                int grow = m0 + wm + mi * 16 + q * 4 + rr;
                int gcol = n0 + wn + ni * 16 + r;
                float v = acc[mi][ni][rr] + bias[gcol];
                if (mode == GM_QKV) {
                    obf[(size_t)grow * Nout + gcol] = __float2bfloat16(v);
                } else if (mode == GM_FC1) {
                    v = 0.5f * v * (1.f + erff(v * 0.70710678118654752f));
                    obf[(size_t)grow * Nout + gcol] = __float2bfloat16(v);
                } else if (mode == GM_PROJ) {
                    int growg = m_base + grow;
                    int wi = growg / 49, n = growg - wi * 49;
                    int b_ = wi >> 6, w64 = wi & 63;
                    int wy = w64 >> 3, wx = w64 & 7;
                    int pin = n / 7, qin = n - pin * 7;
                    int hs = wy * 7 + pin + shift; if (hs >= 56) hs -= 56;
                    int ws2 = wx * 7 + qin + shift; if (ws2 >= 56) ws2 -= 56;
                    size_t t = (size_t)b_ * 3136 + hs * 56 + ws2;
                    xres[t * CDIM + gcol] += v;
                } else {
                    size_t idx = (size_t)(m_base + grow) * CDIM + gcol;
                    float s2 = xres[idx] + v;
                    if (mode == GM_FC2) {
                        xres[idx] = s2;
                    } else {
                        if (isbf) ((bf16*)ofinal)[idx] = __float2bfloat16(s2);
                        else      ((float*)ofinal)[idx] = s2;
                    }
                }
            }
        }
    }
}

// ---------------- windowed attention: one 64-thread block per (window, head) ----------------
__global__ __launch_bounds__(64) void k_attn(const bf16* __restrict__ qkv,
                                             const float* __restrict__ rpb,
                                             bf16* __restrict__ out, int shift,
                                             int wi0) {
    __shared__ float qs[49 * 33];
    __shared__ float ks[49 * 32];
    __shared__ float vs[49 * 32];
    __shared__ float ss[49 * 50];
    __shared__ int reg[64];
    int bid = blockIdx.x;
    int wl = bid / 12, h = bid - wl * 12;
    int wig = wi0 + wl;
    int l = threadIdx.x;

    const bf16* base = qkv + (size_t)wl * 49 * 1152 + h * 32;
    for (int it = 0; it < 25; it++) {
        int idx = l + it * 64;
        if (idx < 1568) {
            int n = idx >> 5, d = idx & 31;
            size_t ro = (size_t)n * 1152 + d;
            qs[n * 33 + d] = __bfloat162float(base[ro]) * SCALE;
            ks[idx] = __bfloat162float(base[ro + 384]);
            vs[idx] = __bfloat162float(base[ro + 768]);
        }
    }
    int w64 = wig & 63;
    int wy = w64 >> 3, wx = w64 & 7;
    if (l < 49) {
        int pin = l / 7, qin = l - pin * 7;
        int pr = wy * 7 + pin, qr = wx * 7 + qin;
        int rp = (pr < 49) ? 0 : (pr < 53 ? 1 : 2);
        int rq = (qr < 49) ? 0 : (qr < 53 ? 1 : 2);
        reg[l] = rp * 3 + rq;
    }
    __syncthreads();
    if (l < 49) {
        float qreg[32];
#pragma unroll
        for (int d = 0; d < 32; d++) qreg[d] = qs[l * 33 + d];
        int pin = l / 7, qin = l - pin * 7;
        float* srow = &ss[l * 50];
        float mx = -1e30f;
        for (int m = 0; m < 49; m++) {
            float s = 0.f;
            const float* kr = &ks[m * 32];
#pragma unroll
            for (int d = 0; d < 32; d++) s += qreg[d] * kr[d];
            int mpin = m / 7, mqin = m - mpin * 7;
            int dy = pin - mpin + 6, dx = qin - mqin + 6;
            s += rpb[(dy * 13 + dx) * 12 + h];
            if (shift > 0 && reg[l] != reg[m]) s -= 100.f;
            srow[m] = s;
            mx = fmaxf(mx, s);
        }
        float sum = 0.f;
        for (int m = 0; m < 49; m++) {
            float e = expf(srow[m] - mx);
            srow[m] = e;
            sum += e;
        }
        float inv = 1.f / sum;
        bf16* op = out + ((size_t)wl * 49 + l) * 384 + h * 32;
        for (int d = 0; d < 32; d++) {
            float o = 0.f;
            for (int m = 0; m < 49; m++) o += srow[m] * vs[m * 32 + d];
            op[d] = __float2bfloat16(o * inv);
        }
    }
}

// ---------------- host launch ----------------
extern "C" void kernel_launch(void* const* d_in, const int* in_sizes, int n_in,
                              void* d_out, int out_size, void* d_ws, size_t ws_size,
                              hipStream_t stream) {
    const void* x       = d_in[0];
    const void* norm1_g = d_in[1];
    const void* norm1_b = d_in[2];
    const void* qkv_w   = d_in[3];
    const void* qkv_b   = d_in[4];
    const void* rpb     = d_in[5];
    const void* proj_w  = d_in[6];
    const void* proj_b  = d_in[7];
    const void* norm2_g = d_in[8];
    const void* norm2_b = d_in[9];
    const void* fc1_w   = d_in[10];
    const void* fc1_b   = d_in[11];
    const void* fc2_w   = d_in[12];
    const void* fc2_b   = d_in[13];
    (void)in_sizes; (void)n_in; (void)out_size; (void)ws_size;

    // workspace layout
    float* xres  = (float*)d_ws;                              // 77,070,336 B
    bf16* lnbuf  = (bf16*)((char*)d_ws + 77070336);           // 38,535,168 B
    char* arena  = (char*)d_ws + 115605504;                   // 38,535,168 B
    bf16* wT     = (bf16*)((char*)d_ws + 154140672);          // 7,077,888 B
    float* prm   = (float*)((char*)d_ws + 161218560);         // 56,160 B
    int* flag    = (int*)((char*)d_ws + 161276672);           // total ~161.28 MB

    bf16* qkvbuf  = (bf16*)arena;                 // 12544*1152*2 = 28,901,376 B
    bf16* attnbuf = (bf16*)(arena + 28901376);    // 12544*384*2  =  9,633,792 B
    bf16* fc1buf  = (bf16*)arena;                 // 12544*1536*2 = 38,535,168 B

    bf16* qkvT  = wT;                          // 2 x 1152*384
    bf16* projT = wT + 884736;                 // 2 x 384*384
    bf16* fc1T  = projT + 294912;              // 2 x 1536*384
    bf16* fc2T  = fc1T + 1179648;              // 2 x 384*1536

    float* p_n1g  = prm;
    float* p_n1b  = prm + 768;
    float* p_qkvb = prm + 1536;
    float* p_rpb  = prm + 3840;
    float* p_pjb  = prm + 7896;
    float* p_n2g  = prm + 8664;
    float* p_n2b  = prm + 9432;
    float* p_f1b  = prm + 10200;
    float* p_f2b  = prm + 13272;

    k_detect<<<1, 64, 0, stream>>>((const unsigned short*)qkv_w, flag);

    k_cvt<<<2, 256, 0, stream>>>(norm1_g, p_n1g, 768, flag);
    k_cvt<<<2, 256, 0, stream>>>(norm1_b, p_n1b, 768, flag);
    k_cvt<<<4, 256, 0, stream>>>(qkv_b, p_qkvb, 2304, flag);
    k_cvt<<<8, 256, 0, stream>>>(rpb, p_rpb, 4056, flag);
    k_cvt<<<2, 256, 0, stream>>>(proj_b, p_pjb, 768, flag);
    k_cvt<<<2, 256, 0, stream>>>(norm2_g, p_n2g, 768, flag);
    k_cvt<<<2, 256, 0, stream>>>(norm2_b, p_n2b, 768, flag);
    k_cvt<<<4, 256, 0, stream>>>(fc1_b, p_f1b, 3072, flag);
    k_cvt<<<2, 256, 0, stream>>>(fc2_b, p_f2b, 768, flag);

    for (int i = 0; i < 2; i++) {
        k_transpose<<<(384 * 1152 + 255) / 256, 256, 0, stream>>>(
            qkv_w, qkvT + (size_t)i * 442368, 384, 1152, (size_t)i * 442368, flag);
        k_transpose<<<(384 * 384 + 255) / 256, 256, 0, stream>>>(
            proj_w, projT + (size_t)i * 147456, 384, 384, (size_t)i * 147456, flag);
        k_transpose<<<(384 * 1536 + 255) / 256, 256, 0, stream>>>(
            fc1_w, fc1T + (size_t)i * 589824, 384, 1536, (size_t)i * 589824, flag);
        k_transpose<<<(1536 * 384 + 255) / 256, 256, 0, stream>>>(
            fc2_w, fc2T + (size_t)i * 589824, 1536, 384, (size_t)i * 589824, flag);
    }
    k_cvt<<<4096, 256, 0, stream>>>(x, xres, TOK * CDIM, flag);

    for (int i = 0; i < 2; i++) {
        int shift = (i == 0) ? 0 : 3;
        k_ln<<<TOK / 4, 256, 0, stream>>>(xres, p_n1g + i * 384, p_n1b + i * 384,
                                          lnbuf, shift, 1);
        for (int c = 0; c < 4; c++) {
            const bf16* Ac = lnbuf + (size_t)c * 12544 * 384;
            k_gemm<<<dim3(98, 9), 256, 0, stream>>>(
                Ac, qkvT + (size_t)i * 442368, p_qkvb + i * 1152, 384, 1152,
                qkvbuf, nullptr, nullptr, GM_QKV, 0, 0, flag);
            k_attn<<<256 * 12, 64, 0, stream>>>(qkvbuf, p_rpb + i * 2028, attnbuf,
                                                shift, c * 256);
            k_gemm<<<dim3(98, 3), 256, 0, stream>>>(
                attnbuf, projT + (size_t)i * 147456, p_pjb + i * 384, 384, 384,
                nullptr, xres, nullptr, GM_PROJ, shift, c * 12544, flag);
        }
        k_ln<<<TOK / 4, 256, 0, stream>>>(xres, p_n2g + i * 384, p_n2b + i * 384,
                                          lnbuf, 0, 0);
        for (int c = 0; c < 4; c++) {
            const bf16* Ac = lnbuf + (size_t)c * 12544 * 384;
            k_gemm<<<dim3(98, 12), 256, 0, stream>>>(
                Ac, fc1T + (size_t)i * 589824, p_f1b + i * 1536, 384, 1536,
                fc1buf, nullptr, nullptr, GM_FC1, 0, 0, flag);
            k_gemm<<<dim3(98, 3), 256, 0, stream>>>(
                fc1buf, fc2T + (size_t)i * 589824, p_f2b + i * 384, 1536, 384,
                nullptr, xres, d_out, (i == 0) ? GM_FC2 : GM_FC2OUT, 0,
                c * 12544, flag);
        }
    }
}

// Round 5
// 1846.220 us; speedup vs baseline: 1.3581x; 1.3581x over previous
//
#include <hip/hip_runtime.h>
#include <hip/hip_bf16.h>
#include <math.h>

using bf16 = __hip_bfloat16;
typedef __bf16 bf16x8 __attribute__((ext_vector_type(8)));
typedef float f32x4 __attribute__((ext_vector_type(4)));

static constexpr int TOK = 16 * 56 * 56;   // 50176 tokens
static constexpr int CDIM = 384;
static constexpr float SCALE = 0.17677669529663687f; // 32^-0.5

// ---------------- convert fp32 input -> fp32 residual (vectorized copy) ----------------
__global__ void k_cvt(const float* __restrict__ x, float* __restrict__ o, int n4) {
    int i = blockIdx.x * blockDim.x + threadIdx.x;
    int stride = gridDim.x * blockDim.x;
    const f32x4* xi = (const f32x4*)x;
    f32x4* oi = (f32x4*)o;
    for (; i < n4; i += stride) oi[i] = xi[i];
}

// ---------------- weight transpose fp32 [K,N] -> bf16 [N,K] ----------------
__global__ void k_transpose(const float* __restrict__ in, bf16* __restrict__ out,
                            int K, int N) {
    int idx = blockIdx.x * 256 + threadIdx.x;
    if (idx >= K * N) return;
    int k = idx / N, n = idx - k * N;
    out[(size_t)n * K + k] = __float2bfloat16(in[idx]);
}

// ---------------- LayerNorm (+ optional roll + window partition) ----------------
__global__ __launch_bounds__(256) void k_ln(const float* __restrict__ xres,
                                            const float* __restrict__ g,
                                            const float* __restrict__ bta,
                                            bf16* __restrict__ out,
                                            int shift, int windowed) {
    int wave = threadIdx.x >> 6, l = threadIdx.x & 63;
    int t = blockIdx.x * 4 + wave;
    int src;
    if (windowed) {
        int wi = t / 49, n = t - wi * 49;
        int b_ = wi >> 6, w64 = wi & 63;
        int wy = w64 >> 3, wx = w64 & 7;
        int pin = n / 7, qin = n - pin * 7;
        int hs = wy * 7 + pin + shift; if (hs >= 56) hs -= 56;
        int ws2 = wx * 7 + qin + shift; if (ws2 >= 56) ws2 -= 56;
        src = b_ * 3136 + hs * 56 + ws2;
    } else {
        src = t;
    }
    const float* xr = xres + (size_t)src * CDIM;
    float v[6];
    float s = 0.f;
#pragma unroll
    for (int j = 0; j < 6; j++) { v[j] = xr[j * 64 + l]; s += v[j]; }
#pragma unroll
    for (int off = 32; off; off >>= 1) s += __shfl_xor(s, off, 64);
    float mean = s * (1.f / 384.f);
    float sq = 0.f;
#pragma unroll
    for (int j = 0; j < 6; j++) { float d = v[j] - mean; sq += d * d; }
#pragma unroll
    for (int off = 32; off; off >>= 1) sq += __shfl_xor(sq, off, 64);
    float rstd = rsqrtf(sq * (1.f / 384.f) + 1e-5f);
    bf16* op = out + (size_t)t * CDIM;
#pragma unroll
    for (int j = 0; j < 6; j++) {
        int c = j * 64 + l;
        float val = (v[j] - mean) * rstd * g[c] + bta[c];
        op[c] = __float2bfloat16(val);
    }
}

// ---------------- MFMA GEMM (m97-style global_load_lds staging) ----------------
#define GM_QKV    0
#define GM_PROJ   1
#define GM_FC1    2
#define GM_FC2    3
#define GM_FC2OUT 4

__device__ __forceinline__ void gld16(const void* g, void* l) {
    __builtin_amdgcn_global_load_lds(
        (const __attribute__((address_space(1))) void*)g,
        (__attribute__((address_space(3))) void*)l, 16, 0, 0);
}

__global__ __launch_bounds__(256) void k_gemm(
    const bf16* __restrict__ A, const bf16* __restrict__ Bt,
    const float* __restrict__ bias, int K, int Nout,
    bf16* __restrict__ obf, float* __restrict__ xres, float* __restrict__ ofinal,
    int mode, int shift, int m_base) {
    __shared__ __align__(16) bf16 As[128 * 32];
    __shared__ __align__(16) bf16 Bs[128 * 32];
    int tid = threadIdx.x;
    int w = tid >> 6, l = tid & 63;
    int m0 = blockIdx.x * 128, n0 = blockIdx.y * 128;
    int wm = (w >> 1) * 64, wn = (w & 1) * 64;

    f32x4 acc[4][4];
#pragma unroll
    for (int i = 0; i < 4; i++)
#pragma unroll
        for (int j = 0; j < 4; j++) acc[i][j] = f32x4{0.f, 0.f, 0.f, 0.f};

    // staging: 512 slots of 16B per matrix; thread t handles slots t, t+256
    int s0 = tid, s1 = tid + 256;
    int ar0 = s0 >> 2, ac0 = (s0 & 3) * 8;
    int ar1 = s1 >> 2, ac1 = (s1 & 3) * 8;
    const bf16* Ab0 = A + (size_t)(m0 + ar0) * K + ac0;
    const bf16* Ab1 = A + (size_t)(m0 + ar1) * K + ac1;
    const bf16* Bb0 = Bt + (size_t)(n0 + ar0) * K + ac0;
    const bf16* Bb1 = Bt + (size_t)(n0 + ar1) * K + ac1;
    char* AsB0 = (char*)As + (size_t)(w * 64) * 16;
    char* AsB1 = (char*)As + (size_t)(w * 64 + 256) * 16;
    char* BsB0 = (char*)Bs + (size_t)(w * 64) * 16;
    char* BsB1 = (char*)Bs + (size_t)(w * 64 + 256) * 16;

    int q = l >> 4, r = l & 15;

    for (int kt = 0; kt < K; kt += 32) {
        gld16(Ab0 + kt, AsB0);
        gld16(Ab1 + kt, AsB1);
        gld16(Bb0 + kt, BsB0);
        gld16(Bb1 + kt, BsB1);
        __syncthreads();
        bf16x8 af[4], bfr[4];
#pragma unroll
        for (int mi = 0; mi < 4; mi++)
            af[mi] = *(const bf16x8*)&As[(wm + mi * 16 + r) * 32 + q * 8];
#pragma unroll
        for (int ni = 0; ni < 4; ni++)
            bfr[ni] = *(const bf16x8*)&Bs[(wn + ni * 16 + r) * 32 + q * 8];
#pragma unroll
        for (int mi = 0; mi < 4; mi++)
#pragma unroll
            for (int ni = 0; ni < 4; ni++)
                acc[mi][ni] = __builtin_amdgcn_mfma_f32_16x16x32_bf16(
                    af[mi], bfr[ni], acc[mi][ni], 0, 0, 0);
        __syncthreads();
    }

    // epilogue: C/D layout col = lane&15, row = (lane>>4)*4 + reg
#pragma unroll
    for (int mi = 0; mi < 4; mi++) {
#pragma unroll
        for (int ni = 0; ni < 4; ni++) {
#pragma unroll
            for (int rr = 0; rr < 4; rr++) {
                int grow = m0 + wm + mi * 16 + q * 4 + rr;  // chunk-local row
                int gcol = n0 + wn + ni * 16 + r;
                float v = acc[mi][ni][rr] + bias[gcol];
                if (mode == GM_QKV) {
                    obf[(size_t)grow * Nout + gcol] = __float2bfloat16(v);
                } else if (mode == GM_FC1) {
                    v = 0.5f * v * (1.f + erff(v * 0.70710678118654752f));
                    obf[(size_t)grow * Nout + gcol] = __float2bfloat16(v);
                } else if (mode == GM_PROJ) {
                    int growg = m_base + grow;
                    int wi = growg / 49, n = growg - wi * 49;
                    int b_ = wi >> 6, w64 = wi & 63;
                    int wy = w64 >> 3, wx = w64 & 7;
                    int pin = n / 7, qin = n - pin * 7;
                    int hs = wy * 7 + pin + shift; if (hs >= 56) hs -= 56;
                    int ws2 = wx * 7 + qin + shift; if (ws2 >= 56) ws2 -= 56;
                    size_t t = (size_t)b_ * 3136 + hs * 56 + ws2;
                    xres[t * CDIM + gcol] += v;
                } else {
                    size_t idx = (size_t)(m_base + grow) * CDIM + gcol;
                    float s2 = xres[idx] + v;
                    if (mode == GM_FC2) xres[idx] = s2;
                    else ofinal[idx] = s2;     // final output is fp32
                }
            }
        }
    }
}

// ---------------- windowed attention v2: wave per (window,head), 4 waves/block ----
// Scores live in registers; K/V staged fp32 in per-wave LDS (broadcast reads).
__device__ __forceinline__ int regionof(int p) {
    return (p < 49) ? 0 : (p < 53 ? 1 : 2);
}

__global__ __launch_bounds__(256) void k_attn(const bf16* __restrict__ qkv,
                                              const float* __restrict__ rpb,
                                              bf16* __restrict__ out, int shift,
                                              int wi0) {
    __shared__ float kv[4][2][49 * 32];   // [wave][k/v] = 50176 B total
    int wave = threadIdx.x >> 6, l = threadIdx.x & 63;
    int p = blockIdx.x * 4 + wave;        // chunk-local (window,head) pair
    int wl = p / 12, h = p - wl * 12;
    int wig = wi0 + wl;
    float* ks = kv[wave][0];
    float* vs = kv[wave][1];

    const bf16* base = qkv + (size_t)wl * 49 * 1152 + h * 32;
    // stage K, V (fp32) cooperatively within the wave
#pragma unroll
    for (int it = 0; it < 25; it++) {
        int idx = l + it * 64;
        if (idx < 1568) {
            int n = idx >> 5, d = idx & 31;
            size_t ro = (size_t)n * 1152 + d;
            ks[idx] = __bfloat162float(base[ro + 384]);
            vs[idx] = __bfloat162float(base[ro + 768]);
        }
    }
    // lane's own Q row
    int active = (l < 49);
    int le = active ? l : 0;
    float qreg[32];
    const bf16* qrow = base + (size_t)le * 1152;
#pragma unroll
    for (int d = 0; d < 32; d++) qreg[d] = __bfloat162float(qrow[d]) * SCALE;
    __syncthreads();   // K/V visible (cross-lane within wave; barrier is cheap & safe)

    int pin = le / 7, qin = le - (le / 7) * 7;
    int w64 = wig & 63;
    int py = (w64 >> 3) * 7, px = (w64 & 7) * 7;
    int regq = regionof(py + pin) * 3 + regionof(px + qin);

    float srow[49];
    float mx = -1e30f;
#pragma unroll
    for (int m = 0; m < 49; m++) {
        const float* kr = &ks[m * 32];
        float s = 0.f;
#pragma unroll
        for (int d = 0; d < 32; d++) s += qreg[d] * kr[d];
        const int mp = m / 7, mq = m - (m / 7) * 7;
        s += rpb[((pin - mp + 6) * 13 + (qin - mq + 6)) * 12 + h];
        if (shift > 0) {
            int regm = regionof(py + mp) * 3 + regionof(px + mq);
            if (regm != regq) s -= 100.f;
        }
        srow[m] = s;
        mx = fmaxf(mx, s);
    }
    float sum = 0.f;
#pragma unroll
    for (int m = 0; m < 49; m++) {
        float e = __expf(srow[m] - mx);
        srow[m] = e;
        sum += e;
    }
    float inv = 1.f / sum;

    float o[32];
#pragma unroll
    for (int d = 0; d < 32; d++) o[d] = 0.f;
#pragma unroll
    for (int m = 0; m < 49; m++) {
        const float* vr = &vs[m * 32];
        float pm = srow[m];
#pragma unroll
        for (int d = 0; d < 32; d++) o[d] += pm * vr[d];
    }
    if (active) {
        bf16* op = out + ((size_t)wl * 49 + l) * 384 + h * 32;
#pragma unroll
        for (int d = 0; d < 32; d++) op[d] = __float2bfloat16(o[d] * inv);
    }
}

// ---------------- host launch ----------------
extern "C" void kernel_launch(void* const* d_in, const int* in_sizes, int n_in,
                              void* d_out, int out_size, void* d_ws, size_t ws_size,
                              hipStream_t stream) {
    const float* x       = (const float*)d_in[0];
    const float* norm1_g = (const float*)d_in[1];
    const float* norm1_b = (const float*)d_in[2];
    const float* qkv_w   = (const float*)d_in[3];
    const float* qkv_b   = (const float*)d_in[4];
    const float* rpb     = (const float*)d_in[5];
    const float* proj_w  = (const float*)d_in[6];
    const float* proj_b  = (const float*)d_in[7];
    const float* norm2_g = (const float*)d_in[8];
    const float* norm2_b = (const float*)d_in[9];
    const float* fc1_w   = (const float*)d_in[10];
    const float* fc1_b   = (const float*)d_in[11];
    const float* fc2_w   = (const float*)d_in[12];
    const float* fc2_b   = (const float*)d_in[13];
    (void)in_sizes; (void)n_in; (void)out_size;

    // pick chunking by available workspace:
    //   chunk=2 needs 77.07+38.54+77.07+7.08 = 199,753,728 B; chunk=4 needs 161.2 MB
    int nc = (ws_size >= (size_t)199753728) ? 2 : 4;
    int rows = TOK / nc;               // 25088 or 12544
    int wins = rows / 49;              // 512 or 256
    size_t arena_sz = (size_t)rows * 1152 * 2 + (size_t)rows * 384 * 2;

    float* xres  = (float*)d_ws;                              // 77,070,336 B
    bf16* lnbuf  = (bf16*)((char*)d_ws + 77070336);           // 38,535,168 B
    char* arena  = (char*)d_ws + 115605504;                   // arena_sz B
    bf16* wT     = (bf16*)((char*)d_ws + 115605504 + arena_sz); // 7,077,888 B

    bf16* qkvbuf  = (bf16*)arena;
    bf16* attnbuf = (bf16*)(arena + (size_t)rows * 1152 * 2);
    bf16* fc1buf  = (bf16*)arena;     // rows*1536*2 <= rows*1152*2 + rows*384*2

    bf16* qkvT  = wT;                          // 2 x 1152*384
    bf16* projT = wT + 884736;                 // 2 x 384*384
    bf16* fc1T  = projT + 294912;              // 2 x 1536*384
    bf16* fc2T  = fc1T + 1179648;              // 2 x 384*1536

    for (int i = 0; i < 2; i++) {
        k_transpose<<<(384 * 1152 + 255) / 256, 256, 0, stream>>>(
            qkv_w + (size_t)i * 442368, qkvT + (size_t)i * 442368, 384, 1152);
        k_transpose<<<(384 * 384 + 255) / 256, 256, 0, stream>>>(
            proj_w + (size_t)i * 147456, projT + (size_t)i * 147456, 384, 384);
        k_transpose<<<(384 * 1536 + 255) / 256, 256, 0, stream>>>(
            fc1_w + (size_t)i * 589824, fc1T + (size_t)i * 589824, 384, 1536);
        k_transpose<<<(1536 * 384 + 255) / 256, 256, 0, stream>>>(
            fc2_w + (size_t)i * 589824, fc2T + (size_t)i * 589824, 1536, 384);
    }
    k_cvt<<<2048, 256, 0, stream>>>(x, xres, TOK * CDIM / 4);

    for (int i = 0; i < 2; i++) {
        int shift = (i == 0) ? 0 : 3;
        k_ln<<<TOK / 4, 256, 0, stream>>>(xres, norm1_g + i * 384, norm1_b + i * 384,
                                          lnbuf, shift, 1);
        for (int c = 0; c < nc; c++) {
            const bf16* Ac = lnbuf + (size_t)c * rows * 384;
            k_gemm<<<dim3(rows / 128, 9), 256, 0, stream>>>(
                Ac, qkvT + (size_t)i * 442368, qkv_b + i * 1152, 384, 1152,
                qkvbuf, nullptr, nullptr, GM_QKV, 0, 0);
            k_attn<<<wins * 12 / 4, 256, 0, stream>>>(qkvbuf, rpb + i * 2028,
                                                      attnbuf, shift, c * wins);
            k_gemm<<<dim3(rows / 128, 3), 256, 0, stream>>>(
                attnbuf, projT + (size_t)i * 147456, proj_b + i * 384, 384, 384,
                nullptr, xres, nullptr, GM_PROJ, shift, c * rows);
        }
        k_ln<<<TOK / 4, 256, 0, stream>>>(xres, norm2_g + i * 384, norm2_b + i * 384,
                                          lnbuf, 0, 0);
        for (int c = 0; c < nc; c++) {
            const bf16* Ac = lnbuf + (size_t)c * rows * 384;
            k_gemm<<<dim3(rows / 128, 12), 256, 0, stream>>>(
                Ac, fc1T + (size_t)i * 589824, fc1_b + i * 1536, 384, 1536,
                fc1buf, nullptr, nullptr, GM_FC1, 0, 0);
            k_gemm<<<dim3(rows / 128, 3), 256, 0, stream>>>(
                fc1buf, fc2T + (size_t)i * 589824, fc2_b + i * 384, 1536, 384,
                nullptr, xres, (float*)d_out, (i == 0) ? GM_FC2 : GM_FC2OUT, 0,
                c * rows);
        }
    }
}